// Round 1
// baseline (424.320 us; speedup 1.0000x reference)
//
#include <hip/hip_runtime.h>
#include <math.h>

#define C 256
#define H 64
#define W 64
#define B 32
#define HW (H*W)
#define EPS 1e-5f
#define LSTR 72    // conv-path LDS feat row stride in shorts (144 B)
#define LSTR2 64   // k1e2 LDS tile stride in shorts (128 B rows; XOR-16 swizzle keeps gathers conflict-free)

typedef __attribute__((ext_vector_type(8))) short short8;   // 8 bf16
typedef __attribute__((ext_vector_type(4))) short short4v;  // 4 bf16
typedef __attribute__((ext_vector_type(4))) float f32x4;

__device__ __forceinline__ float gelu_exact(float z) {
    return 0.5f * z * (1.0f + erff(z * 0.70710678f));
}
__device__ __forceinline__ short f2bf(float f) {
    union { float f; unsigned u; } v; v.f = f;
    unsigned r = v.u + 0x7fffu + ((v.u >> 16) & 1u);
    return (short)(r >> 16);
}
__device__ __forceinline__ float bf2f(short s) {
    union { unsigned u; float f; } v; v.u = ((unsigned)(unsigned short)s) << 16;
    return v.f;
}

__global__ __launch_bounds__(256) void pool_kernel(const float* __restrict__ x,
                                                   float* __restrict__ pooled) {
    int bc = blockIdx.x;
    const float4* p4 = (const float4*)(x + (size_t)bc * HW);
    int t = threadIdx.x;
    float s = 0.f;
    for (int i = t; i < HW/4; i += 256) {
        float4 v = p4[i];
        s += v.x + v.y + v.z + v.w;
    }
    for (int off = 32; off > 0; off >>= 1) s += __shfl_down(s, off, 64);
    __shared__ float wsum[4];
    if ((t & 63) == 0) wsum[t >> 6] = s;
    __syncthreads();
    if (t == 0) pooled[bc] = (wsum[0]+wsum[1]+wsum[2]+wsum[3]) * (1.f/HW);
}

// one block per b; 3 waves, one per expert logit; shuffle-reduce dot product
__global__ void route_kernel(const float* __restrict__ pooled,
                             const float* __restrict__ rw,
                             const float* __restrict__ rb,
                             int* __restrict__ idx) {
    int b = blockIdx.x;
    int t = threadIdx.x;           // 0..191
    int e = t >> 6, lane = t & 63;
    const float* p = pooled + b*C;
    const float* w = rw + e*C;
    float s = 0.f;
#pragma unroll
    for (int i = 0; i < 4; ++i) s += p[lane + i*64] * w[lane + i*64];
    for (int off = 32; off > 0; off >>= 1) s += __shfl_down(s, off, 64);
    __shared__ float lg[3];
    if (lane == 0) lg[e] = s + rb[e];
    __syncthreads();
    if (t == 0) {
        int best = 0; float bv = lg[0];
        if (lg[1] > bv) { bv = lg[1]; best = 1; }
        if (lg[2] > bv) { bv = lg[2]; best = 2; }
        idx[b] = best;   // softmax/temp monotone; w==1 always for top-1
    }
}

// blocks 0..191: pack 6 C*C fp32 matrices into bf16 MFMA fragments:
//   mat 0: pw0_hi  1: pw1_hi  2: pw2_hi  3: e2k_hi  4: pw2_lo  5: e2k_lo
// (lo = bf16(val - float(bf16(val))) — two-term split for ~fp32-accurate e2 path)
// fragment order: chunk (kt,mt): lane holds M[o=mt*16+(lane&15)][ci=kt*32+(lane>>4)*8+j].
// block 192: fold BN into conv weights (kf = k*scale, pad stride 12) + sc/sh tables.
__global__ __launch_bounds__(256) void prep_kernel(
    const float* __restrict__ s0, const float* __restrict__ s1,
    const float* __restrict__ s2, const float* __restrict__ s3,
    const float* __restrict__ e0k, const float* __restrict__ e1k,
    const float* __restrict__ g0, const float* __restrict__ b0,
    const float* __restrict__ m0, const float* __restrict__ v0,
    const float* __restrict__ g1, const float* __restrict__ b1,
    const float* __restrict__ m1, const float* __restrict__ v1,
    const float* __restrict__ g2, const float* __restrict__ b2,
    const float* __restrict__ m2, const float* __restrict__ v2,
    short* __restrict__ apackAll, float* __restrict__ kf0, float* __restrict__ kf1,
    float* __restrict__ scAll, float* __restrict__ shAll)
{
    if (blockIdx.x < 192) {
        int gid = blockIdx.x * 256 + threadIdx.x;       // 0..49151
        int mat = gid >> 13;                            // 0..5
        int c   = gid & 8191;
        int lane = c & 63;
        int ktmt = c >> 6;
        int mt = ktmt & 15, kt = ktmt >> 4;
        int o  = mt*16 + (lane & 15);
        int ci = kt*32 + (lane >> 4)*8;
        const float* src = (mat == 0) ? s0 : (mat == 1) ? s1 :
                           (mat == 2 || mat == 4) ? s2 : s3;
        bool lo = (mat >= 4);
        const float* p = src + o*C + ci;
        short8 v;
#pragma unroll
        for (int j = 0; j < 8; ++j) {
            float f = p[j];
            short hj = f2bf(f);
            v[j] = lo ? f2bf(f - bf2f(hj)) : hj;
        }
        *(short8*)&apackAll[(size_t)gid * 8] = v;
    } else {
        int t = threadIdx.x;   // = ci
        {
            float s = g0[t] / sqrtf(v0[t] + EPS);
            scAll[t] = s; shAll[t] = b0[t] - m0[t]*s;
#pragma unroll
            for (int j = 0; j < 9; ++j) kf0[t*12+j] = e0k[t*9+j]*s;
            kf0[t*12+9] = 0.f; kf0[t*12+10] = 0.f; kf0[t*12+11] = 0.f;
        }
        {
            float s = g1[t] / sqrtf(v1[t] + EPS);
            scAll[C+t] = s; shAll[C+t] = b1[t] - m1[t]*s;
#pragma unroll
            for (int j = 0; j < 9; ++j) kf1[t*12+j] = e1k[t*9+j]*s;
            kf1[t*12+9] = 0.f; kf1[t*12+10] = 0.f; kf1[t*12+11] = 0.f;
        }
        {
            float s = g2[t] / sqrtf(v2[t] + EPS);
            scAll[2*C+t] = s; shAll[2*C+t] = b2[t] - m2[t]*s;
        }
    }
}

// conv for dilation DIL (compile-time so fr[] indexing stays in registers)
template<int DIL>
__device__ __forceinline__ void conv_rows(const float* __restrict__ x,
                                          const float* __restrict__ kf,
                                          const float* __restrict__ sh,
                                          short* __restrict__ lds,
                                          int b, int h, int t) {
    const int strip = t & 7;
    const int w0 = strip * 8;
    const int cib = t >> 3;
#pragma unroll 1
    for (int iter = 0; iter < 8; ++iter) {
        int ci = iter*32 + cib;
        const float* xpl = x + (size_t)(b*C + ci) * HW;
        float fr[3][16];
        bool rv[3];
#pragma unroll
        for (int ky = 0; ky < 3; ++ky) {
            int y = h + (ky - 1)*DIL;
            rv[ky] = ((unsigned)y < H);      // wave-uniform
            if (rv[ky]) {
                const float* row = xpl + y*W;
                float4 fa = (strip > 0) ? *(const float4*)(row + w0 - 4) : float4{0,0,0,0};
                float4 fb = *(const float4*)(row + w0);
                float4 fc = *(const float4*)(row + w0 + 4);
                float4 fd = (strip < 7) ? *(const float4*)(row + w0 + 8) : float4{0,0,0,0};
                fr[ky][0]=fa.x; fr[ky][1]=fa.y; fr[ky][2]=fa.z; fr[ky][3]=fa.w;
                fr[ky][4]=fb.x; fr[ky][5]=fb.y; fr[ky][6]=fb.z; fr[ky][7]=fb.w;
                fr[ky][8]=fc.x; fr[ky][9]=fc.y; fr[ky][10]=fc.z; fr[ky][11]=fc.w;
                fr[ky][12]=fd.x; fr[ky][13]=fd.y; fr[ky][14]=fd.z; fr[ky][15]=fd.w;
            }
        }
        float4 k0 = *(const float4*)(kf + ci*12);
        float4 k1v = *(const float4*)(kf + ci*12 + 4);
        float wk[9] = {k0.x,k0.y,k0.z,k0.w,k1v.x,k1v.y,k1v.z,k1v.w, kf[ci*12+8]};
        float acc8[8] = {0,0,0,0,0,0,0,0};
#pragma unroll
        for (int ky = 0; ky < 3; ++ky) {
            if (rv[ky]) {
#pragma unroll
                for (int kx = 0; kx < 3; ++kx) {
                    float wv = wk[ky*3+kx];
                    const int base = 4 + (kx - 1)*DIL;   // compile-time
#pragma unroll
                    for (int j = 0; j < 8; ++j) acc8[j] += wv * fr[ky][base + j];
                }
            }
        }
        float shv = sh[ci];
        int w0s = w0 ^ ((((unsigned)ci >> 3) & 3) << 4);
        short8 res;
#pragma unroll
        for (int j = 0; j < 8; ++j) res[j] = f2bf(gelu_exact(acc8[j] + shv));
        *(short8*)&lds[ci*LSTR + w0s] = res;
    }
}

// Block = (h, b). Conv experts only (e2 batches handled fully in k1e2).
// Produces feat (bf16, MFMA A-fragment layout): dwconv+BN+gelu.
// featfrag chunk (b, pt, kt): lane holds feat[p=pt*16+(lane&15)][ci=kt*32+(lane>>4)*8+j].
__global__ __launch_bounds__(256) void k1_feat(
    const float* __restrict__ x, const int* __restrict__ idx,
    const float* __restrict__ kf0, const float* __restrict__ kf1,
    const float* __restrict__ scAll, const float* __restrict__ shAll,
    short* __restrict__ featfrag)
{
    __shared__ short lds[C*LSTR];   // 36 KB, [ci][w^swizzle]
    const int h = blockIdx.x, b = blockIdx.y;
    const int t = threadIdx.x;
    const int lane = t & 63, wid = t >> 6;
    const int l15 = lane & 15, quad = lane >> 4;
    const int e = idx[b];
    if (e >= 2) return;

    if (e == 0) conv_rows<1>(x, kf0, shAll,     lds, b, h, t);
    else        conv_rows<2>(x, kf1, shAll + C, lds, b, h, t);
    __syncthreads();
    // transpose LDS [ci][w] -> fragment chunks (coalesced 16B/lane stores)
#pragma unroll
    for (int itr = 0; itr < 8; ++itr) {
        int chunk = itr*4 + wid;          // 0..31
        int kt = chunk & 7, pt = chunk >> 3;
        int wv = pt*16 + l15;
        int cb = kt*32 + quad*8;
        short8 v;
#pragma unroll
        for (int r = 0; r < 8; ++r) {
            int ci = cb + r;
            v[r] = lds[ci*LSTR + (wv ^ ((((unsigned)ci >> 3) & 3) << 4))];
        }
        *(short8*)&featfrag[(((size_t)(b*C + h*4 + pt)*8 + kt)*64 + lane)*8] = v;
    }
}

// 3-product split-bf16 GEMM: acc += (Ahi+Alo)*(Bhi+Blo) - Alo*Blo  (~fp32 accurate).
// A frags from global (pre-packed hi/lo), B frags gathered from hi/lo LDS tiles.
__device__ __forceinline__ void gemm3(const short* __restrict__ aH,
                                      const short* __restrict__ aL,
                                      const short* __restrict__ ldsA,
                                      const short* __restrict__ ldsB,
                                      int lane, int wid, f32x4 acc[4][4])
{
    const int l15 = lane & 15, quad = lane >> 4;
    for (int kt = 0; kt < 8; ++kt) {
        int cb = kt*32 + quad*8;
        short8 bH[4], bL[4];
#pragma unroll
        for (int wt = 0; wt < 4; ++wt) {
            int wv = (wt*16 + l15) ^ (quad << 4);   // ((ci>>3)&3)==quad for these rows
            short8 vH, vL;
#pragma unroll
            for (int r = 0; r < 8; ++r) {
                vH[r] = ldsA[(cb + r)*LSTR2 + wv];
                vL[r] = ldsB[(cb + r)*LSTR2 + wv];
            }
            bH[wt] = vH; bL[wt] = vL;
        }
        short8 fH[4], fL[4];
#pragma unroll
        for (int i = 0; i < 4; ++i) {
            size_t off = ((size_t)(kt*16 + wid*4 + i)*64 + lane)*8;
            fH[i] = *(const short8*)&aH[off];
            fL[i] = *(const short8*)&aL[off];
        }
#pragma unroll
        for (int i = 0; i < 4; ++i)
#pragma unroll
            for (int wt = 0; wt < 4; ++wt) {
                acc[i][wt] = __builtin_amdgcn_mfma_f32_16x16x32_bf16(fH[i], bH[wt], acc[i][wt], 0, 0, 0);
                acc[i][wt] = __builtin_amdgcn_mfma_f32_16x16x32_bf16(fH[i], bL[wt], acc[i][wt], 0, 0, 0);
                acc[i][wt] = __builtin_amdgcn_mfma_f32_16x16x32_bf16(fL[i], bH[wt], acc[i][wt], 0, 0, 0);
            }
    }
}

// e2 expert, fused full path per (h,b) block: x(hi/lo) -> e2k GEMM (3-prod) ->
// BN+gelu -> feat(hi/lo in LDS) -> pw2 GEMM (3-prod) -> +pb -> out (fp32).
// No featfrag round-trip; e2 outputs are ~fp32 exact (bf16-split error ~2^-17).
__global__ __launch_bounds__(256) void k1e2(
    const float* __restrict__ x, const int* __restrict__ idx,
    const float* __restrict__ scAll, const float* __restrict__ shAll,
    const short* __restrict__ apackAll, const float* __restrict__ e2pb,
    float* __restrict__ out)
{
    __shared__ short ldsA[C*LSTR2];   // 32 KB hi tile [ci][w^swz]
    __shared__ short ldsB[C*LSTR2];   // 32 KB lo tile
    const int h = blockIdx.x, b = blockIdx.y;
    const int t = threadIdx.x;
    const int lane = t & 63, wid = t >> 6;
    const int l15 = lane & 15, quad = lane >> 4;
    if (idx[b] != 2) return;

    // stage x row h as bf16 hi/lo
    {
        const int strip = t & 7, w0 = strip*8, cib = t >> 3;
#pragma unroll 1
        for (int iter = 0; iter < 8; ++iter) {
            int ci = iter*32 + cib;
            const float* row = x + ((size_t)(b*C + ci)*H + h)*W;
            float4 fa = *(const float4*)(row + w0);
            float4 fb = *(const float4*)(row + w0 + 4);
            float f[8] = {fa.x,fa.y,fa.z,fa.w,fb.x,fb.y,fb.z,fb.w};
            short8 hi, lo;
#pragma unroll
            for (int j = 0; j < 8; ++j) {
                short hj = f2bf(f[j]);
                hi[j] = hj;
                lo[j] = f2bf(f[j] - bf2f(hj));
            }
            int w0s = w0 ^ ((((unsigned)ci >> 3) & 3) << 4);
            *(short8*)&ldsA[ci*LSTR2 + w0s] = hi;
            *(short8*)&ldsB[ci*LSTR2 + w0s] = lo;
        }
    }
    __syncthreads();

    // GEMM1: z[co][w] = e2k @ x  (split-accurate)
    f32x4 acc[4][4];
#pragma unroll
    for (int i = 0; i < 4; ++i)
#pragma unroll
        for (int wt = 0; wt < 4; ++wt) acc[i][wt] = (f32x4){0.f,0.f,0.f,0.f};
    gemm3(apackAll + (size_t)3*65536, apackAll + (size_t)5*65536,
          ldsA, ldsB, lane, wid, acc);
    __syncthreads();   // all waves done reading x before feat overwrites LDS

    // BN + gelu; split feat to hi/lo tiles in LDS
    {
        const float* sc2 = scAll + 2*C;
        const float* sh2 = shAll + 2*C;
#pragma unroll
        for (int i = 0; i < 4; ++i) {
            int cob = wid*64 + i*16 + quad*4;
            float4 s4 = *(const float4*)&sc2[cob];
            float4 h4 = *(const float4*)&sh2[cob];
            float ss[4] = {s4.x, s4.y, s4.z, s4.w};
            float hh[4] = {h4.x, h4.y, h4.z, h4.w};
#pragma unroll
            for (int r = 0; r < 4; ++r) {
                int co = cob + r;
                int sw = ((co >> 3) & 3) << 4;   // constant over r within this quad row
#pragma unroll
                for (int wt = 0; wt < 4; ++wt) {
                    float f = gelu_exact(acc[i][wt][r]*ss[r] + hh[r]);
                    short hj = f2bf(f);
                    short lj = f2bf(f - bf2f(hj));
                    int a = co*LSTR2 + ((wt*16 + l15) ^ sw);
                    ldsA[a] = hj; ldsB[a] = lj;
                }
            }
        }
    }
    __syncthreads();

    // GEMM2: out[o][w] = pw2 @ feat  (split-accurate)
#pragma unroll
    for (int i = 0; i < 4; ++i)
#pragma unroll
        for (int wt = 0; wt < 4; ++wt) acc[i][wt] = (f32x4){0.f,0.f,0.f,0.f};
    gemm3(apackAll + (size_t)2*65536, apackAll + (size_t)4*65536,
          ldsA, ldsB, lane, wid, acc);

    // epilogue: + pb, store fp32 (16-lane contiguous rows)
#pragma unroll
    for (int i = 0; i < 4; ++i) {
        int ob = wid*64 + i*16 + quad*4;
        float4 p4 = *(const float4*)&e2pb[ob];
        float pbv[4] = {p4.x, p4.y, p4.z, p4.w};
#pragma unroll
        for (int wt = 0; wt < 4; ++wt) {
            int w = wt*16 + l15;
#pragma unroll
            for (int r = 0; r < 4; ++r) {
                out[((size_t)(b*C + ob + r))*HW + h*W + w] = acc[i][wt][r] + pbv[r];
            }
        }
    }
}

// Fragment-direct GEMM, no LDS, no syncthreads. Block tile 128p x 128o.
// D[p][o] = sum_ci feat[p][ci] * pw[o][ci]; A = feat frags, B = pw frags.
// Conv experts only — e2 batches were written by k1e2.
__global__ __launch_bounds__(256) void k2b_out(
    const int* __restrict__ idx, const short* __restrict__ featfrag,
    const short* __restrict__ apackAll,
    const float* __restrict__ e0pb, const float* __restrict__ e1pb,
    float* __restrict__ out)
{
    const int pblk = blockIdx.x;      // 0..31
    const int oblk = blockIdx.y;      // 0..1
    const int b = blockIdx.z;
    const int t = threadIdx.x, lane = t & 63, wid = t >> 6;
    const int l15 = lane & 15, quad = lane >> 4;
    const int e = idx[b];
    if (e >= 2) return;
    const short* pwf = apackAll + (size_t)e * 65536;
    const float* pb = (e == 0) ? e0pb : e1pb;

    f32x4 acc[2][8];
#pragma unroll
    for (int a = 0; a < 2; ++a)
#pragma unroll
        for (int i = 0; i < 8; ++i) acc[a][i] = (f32x4){0.f,0.f,0.f,0.f};

    const short* fbase = featfrag + ((size_t)(b*C + pblk*8 + wid*2)*8)*512;
    for (int kt = 0; kt < 8; ++kt) {
        short8 af[2];
#pragma unroll
        for (int a = 0; a < 2; ++a)
            af[a] = *(const short8*)&fbase[((size_t)(a*8 + kt)*64 + lane)*8];
        short8 bf[8];
#pragma unroll
        for (int i = 0; i < 8; ++i)
            bf[i] = *(const short8*)&pwf[((size_t)(kt*16 + oblk*8 + i)*64 + lane)*8];
#pragma unroll
        for (int a = 0; a < 2; ++a)
#pragma unroll
            for (int i = 0; i < 8; ++i)
                acc[a][i] = __builtin_amdgcn_mfma_f32_16x16x32_bf16(
                    af[a], bf[i], acc[a][i], 0, 0, 0);
    }

#pragma unroll
    for (int i = 0; i < 8; ++i) {
        int o = oblk*128 + i*16 + l15;
        float pbv = pb[o];
#pragma unroll
        for (int a = 0; a < 2; ++a) {
            int p = pblk*128 + wid*32 + a*16 + quad*4;
            f32x4 v = acc[a][i];
            float4 sv = {v[0]+pbv, v[1]+pbv, v[2]+pbv, v[3]+pbv};
            *(float4*)(out + (size_t)(b*C + o)*HW + p) = sv;
        }
    }
}

extern "C" void kernel_launch(void* const* d_in, const int* in_sizes, int n_in,
                              void* d_out, int out_size, void* d_ws, size_t ws_size,
                              hipStream_t stream) {
    const float* x    = (const float*)d_in[0];
    const float* rw   = (const float*)d_in[1];
    const float* rb   = (const float*)d_in[2];
    const float* e0k  = (const float*)d_in[3];
    const float* e0g  = (const float*)d_in[4];
    const float* e0b  = (const float*)d_in[5];
    const float* e0m  = (const float*)d_in[6];
    const float* e0v  = (const float*)d_in[7];
    const float* e0pw = (const float*)d_in[8];
    const float* e0pb = (const float*)d_in[9];
    const float* e1k  = (const float*)d_in[10];
    const float* e1g  = (const float*)d_in[11];
    const float* e1b  = (const float*)d_in[12];
    const float* e1m  = (const float*)d_in[13];
    const float* e1v  = (const float*)d_in[14];
    const float* e1pw = (const float*)d_in[15];
    const float* e1pb = (const float*)d_in[16];
    const float* e2k  = (const float*)d_in[17];
    const float* e2g  = (const float*)d_in[18];
    const float* e2b  = (const float*)d_in[19];
    const float* e2m  = (const float*)d_in[20];
    const float* e2v  = (const float*)d_in[21];
    const float* e2pw = (const float*)d_in[22];
    const float* e2pb = (const float*)d_in[23];
    float* out = (float*)d_out;

    char* wsb = (char*)d_ws;
    float* pooled   = (float*)wsb;                       // 32768 B
    int*   idx      = (int*)(wsb + 32768);               // 128 B
    float* scAll    = (float*)(wsb + 32896);             // 3072 B
    float* shAll    = (float*)(wsb + 35968);             // 3072 B
    float* kf0      = (float*)(wsb + 39040);             // 12288 B
    float* kf1      = (float*)(wsb + 51328);             // 12288 B
    short* apackAll = (short*)(wsb + 63616);             // 786432 B (6 mats)
    short* featfrag = (short*)(wsb + (1u << 20));        // 64 MB

    pool_kernel<<<B*C, 256, 0, stream>>>(x, pooled);
    route_kernel<<<B, 192, 0, stream>>>(pooled, rw, rb, idx);
    prep_kernel<<<193, 256, 0, stream>>>(e0pw, e1pw, e2pw, e2k, e0k, e1k,
                                         e0g, e0b, e0m, e0v,
                                         e1g, e1b, e1m, e1v,
                                         e2g, e2b, e2m, e2v,
                                         apackAll, kf0, kf1, scAll, shAll);
    k1_feat<<<dim3(H, B), 256, 0, stream>>>(x, idx, kf0, kf1, scAll, shAll,
                                            featfrag);
    k1e2<<<dim3(H, B), 256, 0, stream>>>(x, idx, scAll, shAll, apackAll,
                                         e2pb, out);
    k2b_out<<<dim3(32, 2, B), 256, 0, stream>>>(idx, featfrag, apackAll,
                                                e0pb, e1pb, out);
}

// Round 2
// 407.179 us; speedup vs baseline: 1.0421x; 1.0421x over previous
//
#include <hip/hip_runtime.h>
#include <math.h>

#define C 256
#define H 64
#define W 64
#define B 32
#define HW (H*W)
#define EPS 1e-5f
#define LSTR2 256  // shorts per row of the [w][ci] LDS tile (512 B)

typedef __attribute__((ext_vector_type(8))) short short8;   // 8 bf16
typedef __attribute__((ext_vector_type(4))) short short4v;  // 4 bf16
typedef __attribute__((ext_vector_type(4))) float f32x4;

__device__ __forceinline__ float gelu_exact(float z) {
    return 0.5f * z * (1.0f + erff(z * 0.70710678f));
}
__device__ __forceinline__ short f2bf(float f) {
    union { float f; unsigned u; } v; v.f = f;
    unsigned r = v.u + 0x7fffu + ((v.u >> 16) & 1u);
    return (short)(r >> 16);
}
__device__ __forceinline__ float bf2f(short s) {
    union { unsigned u; float f; } v; v.u = ((unsigned)(unsigned short)s) << 16;
    return v.f;
}
// XOR-swizzle (short-index units, 8-short groups) for the [w][ci] tiles.
// Balanced for both readers (16 consecutive w rows -> 2-way, free) and
// writers (w = j mod 8 strided rows -> 8 distinct slots).
__device__ __forceinline__ int swz8(int w) {
    return (((w & 7) ^ ((w >> 3) & 7)) << 3);
}
// XCD-aware (h,b) remap: each XCD gets 8-consecutive-h chunks (halo rows L2-hit),
// rotated across b so all XCDs get every batch (load-balanced vs expert routing).
__device__ __forceinline__ void swz_hb(int bx, int by, int& h, int& b) {
    int wg  = bx + (by << 6);
    int xcd = wg & 7, lin = wg >> 3;
    b = lin >> 3;
    int j = lin & 7;
    h = (((xcd + b) & 7) << 3) + j;
}

__global__ __launch_bounds__(256) void pool_kernel(const float* __restrict__ x,
                                                   float* __restrict__ pooled) {
    int bc = blockIdx.x;
    const float4* p4 = (const float4*)(x + (size_t)bc * HW);
    int t = threadIdx.x;
    float s = 0.f;
    for (int i = t; i < HW/4; i += 256) {
        float4 v = p4[i];
        s += v.x + v.y + v.z + v.w;
    }
    for (int off = 32; off > 0; off >>= 1) s += __shfl_down(s, off, 64);
    __shared__ float wsum[4];
    if ((t & 63) == 0) wsum[t >> 6] = s;
    __syncthreads();
    if (t == 0) pooled[bc] = (wsum[0]+wsum[1]+wsum[2]+wsum[3]) * (1.f/HW);
}

// blocks 0..191: pack 6 C*C fp32 matrices into bf16 MFMA fragments:
//   mat 0: pw0_hi  1: pw1_hi  2: pw2_hi  3: e2k_hi  4: pw2_lo  5: e2k_lo
// fragment chunk (kt,mt): lane holds M[o=mt*16+(lane&15)][ci=kt*32+(lane>>4)*8+j].
// block 192: fold BN into conv weights + sc/sh tables.
// block 193: routing (argmax logit; softmax/temp monotone, top-1 weight == 1).
__global__ __launch_bounds__(256) void prep_kernel(
    const float* __restrict__ s0, const float* __restrict__ s1,
    const float* __restrict__ s2, const float* __restrict__ s3,
    const float* __restrict__ e0k, const float* __restrict__ e1k,
    const float* __restrict__ g0, const float* __restrict__ b0,
    const float* __restrict__ m0, const float* __restrict__ v0,
    const float* __restrict__ g1, const float* __restrict__ b1,
    const float* __restrict__ m1, const float* __restrict__ v1,
    const float* __restrict__ g2, const float* __restrict__ b2,
    const float* __restrict__ m2, const float* __restrict__ v2,
    const float* __restrict__ pooled, const float* __restrict__ rw,
    const float* __restrict__ rb, int* __restrict__ idx,
    short* __restrict__ apackAll, float* __restrict__ kf0, float* __restrict__ kf1,
    float* __restrict__ scAll, float* __restrict__ shAll)
{
    if (blockIdx.x < 192) {
        int gid = blockIdx.x * 256 + threadIdx.x;       // 0..49151
        int mat = gid >> 13;                            // 0..5
        int c   = gid & 8191;
        int lane = c & 63;
        int ktmt = c >> 6;
        int mt = ktmt & 15, kt = ktmt >> 4;
        int o  = mt*16 + (lane & 15);
        int ci = kt*32 + (lane >> 4)*8;
        const float* src = (mat == 0) ? s0 : (mat == 1) ? s1 :
                           (mat == 2 || mat == 4) ? s2 : s3;
        bool lo = (mat >= 4);
        const float* p = src + o*C + ci;
        short8 v;
#pragma unroll
        for (int j = 0; j < 8; ++j) {
            float f = p[j];
            short hj = f2bf(f);
            v[j] = lo ? f2bf(f - bf2f(hj)) : hj;
        }
        *(short8*)&apackAll[(size_t)gid * 8] = v;
    } else if (blockIdx.x == 192) {
        int t = threadIdx.x;   // = ci
        {
            float s = g0[t] / sqrtf(v0[t] + EPS);
            scAll[t] = s; shAll[t] = b0[t] - m0[t]*s;
#pragma unroll
            for (int j = 0; j < 9; ++j) kf0[t*12+j] = e0k[t*9+j]*s;
            kf0[t*12+9] = 0.f; kf0[t*12+10] = 0.f; kf0[t*12+11] = 0.f;
        }
        {
            float s = g1[t] / sqrtf(v1[t] + EPS);
            scAll[C+t] = s; shAll[C+t] = b1[t] - m1[t]*s;
#pragma unroll
            for (int j = 0; j < 9; ++j) kf1[t*12+j] = e1k[t*9+j]*s;
            kf1[t*12+9] = 0.f; kf1[t*12+10] = 0.f; kf1[t*12+11] = 0.f;
        }
        {
            float s = g2[t] / sqrtf(v2[t] + EPS);
            scAll[2*C+t] = s; shAll[2*C+t] = b2[t] - m2[t]*s;
        }
    } else {
        int t = threadIdx.x;           // use 0..191: (b? no) e = t>>6, lane = t&63
        if (t < 192) {
            int e = t >> 6, lane = t & 63;
            __shared__ float lg[3*B];
            for (int b = 0; b < B; ++b) {
                const float* p = pooled + b*C;
                const float* w = rw + e*C;
                float s = 0.f;
#pragma unroll
                for (int i = 0; i < 4; ++i) s += p[lane + i*64] * w[lane + i*64];
                for (int off = 32; off > 0; off >>= 1) s += __shfl_down(s, off, 64);
                if (lane == 0) lg[b*3 + e] = s + rb[e];
            }
            __syncthreads();
            if (t < B) {
                float l0 = lg[t*3], l1 = lg[t*3+1], l2 = lg[t*3+2];
                int best = 0; float bv = l0;
                if (l1 > bv) { bv = l1; best = 1; }
                if (l2 > bv) { bv = l2; best = 2; }
                idx[t] = best;
            }
        } else {
            __syncthreads();   // keep barrier uniform across the block
        }
    }
}

// conv for dilation DIL; writes gelu(BN(conv)) bf16 TRANSPOSED into lds[w][ci^swz]
template<int DIL>
__device__ __forceinline__ void conv_rows_t(const float* __restrict__ x,
                                            const float* __restrict__ kf,
                                            const float* __restrict__ sh,
                                            short* __restrict__ lds,
                                            int b, int h, int t) {
    const int strip = t & 7;
    const int w0 = strip * 8;
    const int cib = t >> 3;
#pragma unroll 1
    for (int iter = 0; iter < 8; ++iter) {
        int ci = iter*32 + cib;
        const float* xpl = x + (size_t)(b*C + ci) * HW;
        float fr[3][16];
        bool rv[3];
#pragma unroll
        for (int ky = 0; ky < 3; ++ky) {
            int y = h + (ky - 1)*DIL;
            rv[ky] = ((unsigned)y < H);      // wave-uniform
            if (rv[ky]) {
                const float* row = xpl + y*W;
                float4 fa = (strip > 0) ? *(const float4*)(row + w0 - 4) : float4{0,0,0,0};
                float4 fb = *(const float4*)(row + w0);
                float4 fc = *(const float4*)(row + w0 + 4);
                float4 fd = (strip < 7) ? *(const float4*)(row + w0 + 8) : float4{0,0,0,0};
                fr[ky][0]=fa.x; fr[ky][1]=fa.y; fr[ky][2]=fa.z; fr[ky][3]=fa.w;
                fr[ky][4]=fb.x; fr[ky][5]=fb.y; fr[ky][6]=fb.z; fr[ky][7]=fb.w;
                fr[ky][8]=fc.x; fr[ky][9]=fc.y; fr[ky][10]=fc.z; fr[ky][11]=fc.w;
                fr[ky][12]=fd.x; fr[ky][13]=fd.y; fr[ky][14]=fd.z; fr[ky][15]=fd.w;
            }
        }
        float4 k0 = *(const float4*)(kf + ci*12);
        float4 k1v = *(const float4*)(kf + ci*12 + 4);
        float wk[9] = {k0.x,k0.y,k0.z,k0.w,k1v.x,k1v.y,k1v.z,k1v.w, kf[ci*12+8]};
        float acc8[8] = {0,0,0,0,0,0,0,0};
#pragma unroll
        for (int ky = 0; ky < 3; ++ky) {
            if (rv[ky]) {
#pragma unroll
                for (int kx = 0; kx < 3; ++kx) {
                    float wv = wk[ky*3+kx];
                    const int base = 4 + (kx - 1)*DIL;   // compile-time
#pragma unroll
                    for (int j = 0; j < 8; ++j) acc8[j] += wv * fr[ky][base + j];
                }
            }
        }
        float shv = sh[ci];
#pragma unroll
        for (int j = 0; j < 8; ++j) {
            int w = w0 + j;
            lds[w*LSTR2 + (ci ^ swz8(w))] = f2bf(gelu_exact(acc8[j] + shv));
        }
    }
}

// Conv experts, fully fused per (h,b): dwconv+BN+gelu -> feat[w][ci] in LDS ->
// GEMM2 (pw_hi frags from global, feat B-frags via ds_read_b128) -> +pb -> out.
__global__ __launch_bounds__(256) void kconv(
    const float* __restrict__ x, const int* __restrict__ idx,
    const float* __restrict__ kf0, const float* __restrict__ kf1,
    const float* __restrict__ shAll, const short* __restrict__ apackAll,
    const float* __restrict__ e0pb, const float* __restrict__ e1pb,
    float* __restrict__ out)
{
    __shared__ short lds[W*LSTR2];   // 32 KB, [w][ci^swz]
    int h, b;
    swz_hb(blockIdx.x, blockIdx.y, h, b);
    const int e = idx[b];
    if (e >= 2) return;
    const int t = threadIdx.x;
    const int lane = t & 63, wid = t >> 6;
    const int l15 = lane & 15, quad = lane >> 4;

    if (e == 0) conv_rows_t<1>(x, kf0, shAll,     lds, b, h, t);
    else        conv_rows_t<2>(x, kf1, shAll + C, lds, b, h, t);
    __syncthreads();

    // GEMM2: D[o][w] = pw . feat ; wave wid owns o = wid*64..+63
    const short* pwf = apackAll + (size_t)e * 65536;
    f32x4 acc[4][4];
#pragma unroll
    for (int i = 0; i < 4; ++i)
#pragma unroll
        for (int wt = 0; wt < 4; ++wt) acc[i][wt] = (f32x4){0.f,0.f,0.f,0.f};
    for (int kt = 0; kt < 8; ++kt) {
        short8 bf[4];
#pragma unroll
        for (int wt = 0; wt < 4; ++wt) {
            int w = wt*16 + l15;
            bf[wt] = *(const short8*)&lds[w*LSTR2 + ((kt*32 + quad*8) ^ swz8(w))];
        }
        short8 af[4];
#pragma unroll
        for (int i = 0; i < 4; ++i)
            af[i] = *(const short8*)&pwf[((size_t)(kt*16 + wid*4 + i)*64 + lane)*8];
#pragma unroll
        for (int i = 0; i < 4; ++i)
#pragma unroll
            for (int wt = 0; wt < 4; ++wt)
                acc[i][wt] = __builtin_amdgcn_mfma_f32_16x16x32_bf16(
                    af[i], bf[wt], acc[i][wt], 0, 0, 0);
    }

    const float* pb = (e == 0) ? e0pb : e1pb;
#pragma unroll
    for (int i = 0; i < 4; ++i) {
        int ob = wid*64 + i*16 + quad*4;
        float4 p4 = *(const float4*)&pb[ob];
        float pbv[4] = {p4.x, p4.y, p4.z, p4.w};
#pragma unroll
        for (int wt = 0; wt < 4; ++wt) {
            int w = wt*16 + l15;
#pragma unroll
            for (int r = 0; r < 4; ++r)
                out[((size_t)(b*C + ob + r))*HW + h*W + w] = acc[i][wt][r] + pbv[r];
        }
    }
}

// 3-product split-bf16 GEMM over [w][ci] hi/lo LDS tiles (ds_read_b128 B-frags):
// acc += Ahi*Bhi + Ahi*Blo + Alo*Bhi  (~fp32 accurate; lo*lo term ~2^-18 dropped)
__device__ __forceinline__ void gemm3t(const short* __restrict__ aH,
                                       const short* __restrict__ aL,
                                       const short* __restrict__ ldsH,
                                       const short* __restrict__ ldsL,
                                       int lane, int wid, f32x4 acc[4][4])
{
    const int l15 = lane & 15, quad = lane >> 4;
    for (int kt = 0; kt < 8; ++kt) {
        short8 bH[4], bL[4];
#pragma unroll
        for (int wt = 0; wt < 4; ++wt) {
            int w = wt*16 + l15;
            int off = w*LSTR2 + ((kt*32 + quad*8) ^ swz8(w));
            bH[wt] = *(const short8*)&ldsH[off];
            bL[wt] = *(const short8*)&ldsL[off];
        }
        short8 fH[4], fL[4];
#pragma unroll
        for (int i = 0; i < 4; ++i) {
            size_t off = ((size_t)(kt*16 + wid*4 + i)*64 + lane)*8;
            fH[i] = *(const short8*)&aH[off];
            fL[i] = *(const short8*)&aL[off];
        }
#pragma unroll
        for (int i = 0; i < 4; ++i)
#pragma unroll
            for (int wt = 0; wt < 4; ++wt) {
                acc[i][wt] = __builtin_amdgcn_mfma_f32_16x16x32_bf16(fH[i], bH[wt], acc[i][wt], 0, 0, 0);
                acc[i][wt] = __builtin_amdgcn_mfma_f32_16x16x32_bf16(fH[i], bL[wt], acc[i][wt], 0, 0, 0);
                acc[i][wt] = __builtin_amdgcn_mfma_f32_16x16x32_bf16(fL[i], bH[wt], acc[i][wt], 0, 0, 0);
            }
    }
}

// e2 expert, fused full path per (h,b): x hi/lo [w][ci] tiles -> e2k GEMM (3-prod)
// -> BN+gelu -> feat hi/lo tiles -> pw2 GEMM (3-prod) -> +pb -> out (fp32).
__global__ __launch_bounds__(256) void ke2(
    const float* __restrict__ x, const int* __restrict__ idx,
    const float* __restrict__ scAll, const float* __restrict__ shAll,
    const short* __restrict__ apackAll, const float* __restrict__ e2pb,
    float* __restrict__ out)
{
    __shared__ short ldsH[W*LSTR2];   // 32 KB hi tile [w][ci^swz]
    __shared__ short ldsL[W*LSTR2];   // 32 KB lo tile
    int h, b;
    swz_hb(blockIdx.x, blockIdx.y, h, b);
    if (idx[b] != 2) return;
    const int t = threadIdx.x;
    const int lane = t & 63, wid = t >> 6;
    const int l15 = lane & 15, quad = lane >> 4;

    // stage x row h: channel-direction loads (lane = w -> 256B/inst coalesced),
    // 16B LDS row writes
    {
        const int w = t & 63;
        const int vsw = swz8(w);
        const int ci0w = wid * 64;
#pragma unroll 1
        for (int k = 0; k < 8; ++k) {
            int ci0 = ci0w + k*8;
            const float* px = x + ((size_t)(b*C + ci0)*H + h)*W + w;
            float f[8];
#pragma unroll
            for (int j = 0; j < 8; ++j) f[j] = px[(size_t)j * HW];
            short8 hi, lo;
#pragma unroll
            for (int j = 0; j < 8; ++j) {
                short hj = f2bf(f[j]);
                hi[j] = hj;
                lo[j] = f2bf(f[j] - bf2f(hj));
            }
            int col = ci0 ^ vsw;
            *(short8*)&ldsH[w*LSTR2 + col] = hi;
            *(short8*)&ldsL[w*LSTR2 + col] = lo;
        }
    }
    __syncthreads();

    // GEMM1: z[co][w] = e2k @ x  (split-accurate)
    f32x4 acc[4][4];
#pragma unroll
    for (int i = 0; i < 4; ++i)
#pragma unroll
        for (int wt = 0; wt < 4; ++wt) acc[i][wt] = (f32x4){0.f,0.f,0.f,0.f};
    gemm3t(apackAll + (size_t)3*65536, apackAll + (size_t)5*65536,
           ldsH, ldsL, lane, wid, acc);
    __syncthreads();   // all waves done reading x before feat overwrites tiles

    // BN + gelu; split feat hi/lo, store transposed [w][co]
    {
        const float* sc2 = scAll + 2*C;
        const float* sh2 = shAll + 2*C;
#pragma unroll
        for (int i = 0; i < 4; ++i) {
            int cob = wid*64 + i*16 + quad*4;
            float4 s4 = *(const float4*)&sc2[cob];
            float4 h4 = *(const float4*)&sh2[cob];
            float ss[4] = {s4.x, s4.y, s4.z, s4.w};
            float hh[4] = {h4.x, h4.y, h4.z, h4.w};
#pragma unroll
            for (int wt = 0; wt < 4; ++wt) {
                int w = wt*16 + l15;
                int col = cob ^ swz8(w);   // swz flips bits>=3: 4-short groups preserved
                short4v ph, pl;
#pragma unroll
                for (int r = 0; r < 4; ++r) {
                    float f = gelu_exact(acc[i][wt][r]*ss[r] + hh[r]);
                    short hj = f2bf(f);
                    ph[r] = hj;
                    pl[r] = f2bf(f - bf2f(hj));
                }
                *(short4v*)&ldsH[w*LSTR2 + col] = ph;
                *(short4v*)&ldsL[w*LSTR2 + col] = pl;
            }
        }
    }
    __syncthreads();

    // GEMM2: out[o][w] = pw2 @ feat  (split-accurate)
#pragma unroll
    for (int i = 0; i < 4; ++i)
#pragma unroll
        for (int wt = 0; wt < 4; ++wt) acc[i][wt] = (f32x4){0.f,0.f,0.f,0.f};
    gemm3t(apackAll + (size_t)2*65536, apackAll + (size_t)4*65536,
           ldsH, ldsL, lane, wid, acc);

    // epilogue: + pb, store fp32
#pragma unroll
    for (int i = 0; i < 4; ++i) {
        int ob = wid*64 + i*16 + quad*4;
        float4 p4 = *(const float4*)&e2pb[ob];
        float pbv[4] = {p4.x, p4.y, p4.z, p4.w};
#pragma unroll
        for (int wt = 0; wt < 4; ++wt) {
            int w = wt*16 + l15;
#pragma unroll
            for (int r = 0; r < 4; ++r)
                out[((size_t)(b*C + ob + r))*HW + h*W + w] = acc[i][wt][r] + pbv[r];
        }
    }
}

extern "C" void kernel_launch(void* const* d_in, const int* in_sizes, int n_in,
                              void* d_out, int out_size, void* d_ws, size_t ws_size,
                              hipStream_t stream) {
    const float* x    = (const float*)d_in[0];
    const float* rw   = (const float*)d_in[1];
    const float* rb   = (const float*)d_in[2];
    const float* e0k  = (const float*)d_in[3];
    const float* e0g  = (const float*)d_in[4];
    const float* e0b  = (const float*)d_in[5];
    const float* e0m  = (const float*)d_in[6];
    const float* e0v  = (const float*)d_in[7];
    const float* e0pw = (const float*)d_in[8];
    const float* e0pb = (const float*)d_in[9];
    const float* e1k  = (const float*)d_in[10];
    const float* e1g  = (const float*)d_in[11];
    const float* e1b  = (const float*)d_in[12];
    const float* e1m  = (const float*)d_in[13];
    const float* e1v  = (const float*)d_in[14];
    const float* e1pw = (const float*)d_in[15];
    const float* e1pb = (const float*)d_in[16];
    const float* e2k  = (const float*)d_in[17];
    const float* e2g  = (const float*)d_in[18];
    const float* e2b  = (const float*)d_in[19];
    const float* e2m  = (const float*)d_in[20];
    const float* e2v  = (const float*)d_in[21];
    const float* e2pw = (const float*)d_in[22];
    const float* e2pb = (const float*)d_in[23];
    float* out = (float*)d_out;

    char* wsb = (char*)d_ws;
    float* pooled   = (float*)wsb;                       // 32768 B
    int*   idx      = (int*)(wsb + 32768);               // 128 B
    float* scAll    = (float*)(wsb + 32896);             // 3072 B
    float* shAll    = (float*)(wsb + 35968);             // 3072 B
    float* kf0      = (float*)(wsb + 39040);             // 12288 B
    float* kf1      = (float*)(wsb + 51328);             // 12288 B
    short* apackAll = (short*)(wsb + 63616);             // 786432 B (6 mats)

    pool_kernel<<<B*C, 256, 0, stream>>>(x, pooled);
    prep_kernel<<<194, 256, 0, stream>>>(e0pw, e1pw, e2pw, e2k, e0k, e1k,
                                         e0g, e0b, e0m, e0v,
                                         e1g, e1b, e1m, e1v,
                                         e2g, e2b, e2m, e2v,
                                         pooled, rw, rb, idx,
                                         apackAll, kf0, kf1, scAll, shAll);
    kconv<<<dim3(H, B), 256, 0, stream>>>(x, idx, kf0, kf1, shAll, apackAll,
                                          e0pb, e1pb, out);
    ke2<<<dim3(H, B), 256, 0, stream>>>(x, idx, scAll, shAll, apackAll,
                                        e2pb, out);
}